// Round 7
// baseline (218.990 us; speedup 1.0000x reference)
//
#include <hip/hip_runtime.h>
#include <math.h>

#define B_   4
#define N_   4096
#define C_   512
#define C8_  64
#define C2_  256
#define LOG2E 1.4426950408889634f

typedef __attribute__((ext_vector_type(8))) short bf16x8;
typedef __attribute__((ext_vector_type(4))) short bf16x4;
typedef __attribute__((ext_vector_type(4))) float floatx4;
typedef __attribute__((ext_vector_type(16))) float floatx16;
typedef __attribute__((ext_vector_type(2))) unsigned uint32x2;

__device__ __forceinline__ short f2bf(float x) {
    unsigned u = __float_as_uint(x);
    u += 0x7fff + ((u >> 16) & 1);          // round-to-nearest-even
    return (short)(u >> 16);
}
__device__ __forceinline__ unsigned cvtpk(float a, float b) {
    unsigned r;
    asm("v_cvt_pk_bf16_f32 %0, %1, %2" : "=v"(r) : "v"(a), "v"(b));
    return r;   // lo = bf16(a), hi = bf16(b)
}
__device__ __forceinline__ float bf2f(short s) {
    return __uint_as_float(((unsigned)(unsigned short)s) << 16);
}

union U8 { bf16x8 v; unsigned u[4]; };
union U4 { bf16x4 v; unsigned u[2]; };

// ---------------------------------------------------------------------------
// Kernel 1: qkv MFMA GEMM, fully fused input conversion (NO prep kernel).
// As: x fp32 -> cvtpk -> bf16 (pattern proven rounds 0-4).
// Bs: raw Wf/Wg/Wh fp32 transpose-staged into LDS: each thread reads 16
// consecutive n (float4, coalesced; W rows are n-contiguous, L2-resident)
// at one k and scatter-writes b16 into the k-contiguous Bs layout.
// 64x128 tiles, grid (3,256)=768 blocks = 3/CU, LB(256,3).
// g (queries) pre-scaled by log2(e) for exp2-direct softmax.
// ---------------------------------------------------------------------------
__global__ __launch_bounds__(256, 3) void qkv_mfma(
    const float* __restrict__ x,
    const float* __restrict__ Wf, const float* __restrict__ Wg,
    const float* __restrict__ Wh,
    const float* __restrict__ bfv, const float* __restrict__ bgv,
    const float* __restrict__ bhv,
    short* __restrict__ fbf, short* __restrict__ gbf, short* __restrict__ hT)
{
    const int ny = blockIdx.x;           // 0..2
    const int m0 = blockIdx.y * 64;
    const int t  = threadIdx.x;
    const int w  = t >> 6, lane = t & 63;
    const int l15 = lane & 15, quad = lane >> 4;
    const int wm = w & 1, wn = w >> 1;   // wave: 32 rows x 64 cols

    __shared__ short As[64 * 40];
    __shared__ short Bs[128 * 40];

    // W transpose-staging geometry (fixed per thread)
    const int kk = t >> 3;               // 0..31 (k within tile)
    const int nl = (t & 7) * 16;         // 0..112 (n within 128-col block)
    const float* wsrc; int wcol, wod;
    if (ny == 0) {
        if (nl < 64) { wsrc = Wf; wcol = nl; }
        else         { wsrc = Wg; wcol = nl - 64; }
        wod = 64;
    } else {
        wsrc = Wh; wcol = (ny - 1) * 128 + nl; wod = 256;
    }
    const int arow = t >> 2, ako = (t & 3) * 8;   // As: 8 k-elems per thread

    floatx4 acc[2][4];
    #pragma unroll
    for (int i = 0; i < 2; i++)
        #pragma unroll
        for (int j = 0; j < 4; j++) acc[i][j] = (floatx4){0.f,0.f,0.f,0.f};

    for (int k0 = 0; k0 < C_; k0 += 32) {
        {   // As: 64 rows x 32 k from x fp32
            const float* xp = &x[(size_t)(m0 + arow) * C_ + k0 + ako];
            float4 v0 = *(const float4*)xp;
            float4 v1 = *(const float4*)(xp + 4);
            U8 ua;
            ua.u[0] = cvtpk(v0.x, v0.y); ua.u[1] = cvtpk(v0.z, v0.w);
            ua.u[2] = cvtpk(v1.x, v1.y); ua.u[3] = cvtpk(v1.z, v1.w);
            *(bf16x8*)&As[arow * 40 + ako] = ua.v;
        }
        {   // Bs: transpose-stage 16 n at one k from raw W
            const float* rp = &wsrc[(size_t)(k0 + kk) * wod + wcol];
            #pragma unroll
            for (int i = 0; i < 4; i++) {
                float4 wv = *(const float4*)&rp[i * 4];
                Bs[(nl + i * 4 + 0) * 40 + kk] = f2bf(wv.x);
                Bs[(nl + i * 4 + 1) * 40 + kk] = f2bf(wv.y);
                Bs[(nl + i * 4 + 2) * 40 + kk] = f2bf(wv.z);
                Bs[(nl + i * 4 + 3) * 40 + kk] = f2bf(wv.w);
            }
        }
        __syncthreads();

        bf16x8 af[2], bfr[4];
        #pragma unroll
        for (int mt = 0; mt < 2; mt++)
            af[mt] = *(const bf16x8*)&As[(wm * 32 + mt * 16 + l15) * 40 + quad * 8];
        #pragma unroll
        for (int nt = 0; nt < 4; nt++)
            bfr[nt] = *(const bf16x8*)&Bs[(wn * 64 + nt * 16 + l15) * 40 + quad * 8];
        #pragma unroll
        for (int mt = 0; mt < 2; mt++)
            #pragma unroll
            for (int nt = 0; nt < 4; nt++)
                acc[mt][nt] = __builtin_amdgcn_mfma_f32_16x16x32_bf16(af[mt], bfr[nt], acc[mt][nt], 0, 0, 0);
        __syncthreads();
    }

    if (ny == 0) {
        #pragma unroll
        for (int mt = 0; mt < 2; mt++) {
            #pragma unroll
            for (int nt = 0; nt < 4; nt++) {
                int cn = wn * 64 + nt * 16 + l15;
                #pragma unroll
                for (int rg = 0; rg < 4; rg++) {
                    int row = m0 + wm * 32 + mt * 16 + quad * 4 + rg;
                    float v = acc[mt][nt][rg];
                    if (cn < 64) fbf[(size_t)row * 64 + cn]        = f2bf(v + bfv[cn]);
                    else         gbf[(size_t)row * 64 + (cn - 64)] = f2bf((v + bgv[cn - 64]) * LOG2E);
                }
            }
        }
    } else {
        #pragma unroll
        for (int mt = 0; mt < 2; mt++) {
            #pragma unroll
            for (int nt = 0; nt < 4; nt++) {
                int hch = (ny - 1) * 128 + wn * 64 + nt * 16 + l15;
                int row = m0 + wm * 32 + mt * 16 + quad * 4;
                int bb = row >> 12, n = row & 4095;
                float bias = bhv[hch];
                U4 pk;
                pk.u[0] = cvtpk(acc[mt][nt][0] + bias, acc[mt][nt][1] + bias);
                pk.u[1] = cvtpk(acc[mt][nt][2] + bias, acc[mt][nt][3] + bias);
                *(bf16x4*)&hT[((size_t)(bb * 256 + hch)) * 4096 + n] = pk.v;
            }
        }
    }
}

// ---------------------------------------------------------------------------
// Kernel 2: attention v6 (UNCHANGED — proven at 66.7 µs, Occ ~20%, 0 bank
// conflicts, WRITE 16.5 MB).  Per-wave 32 q x 128 vch; ~184 unified regs ->
// 2 blocks/CU.  nsplit=2, 512 blocks, partial O in bf16.
// ---------------------------------------------------------------------------
#define HST 40   // short stride for fs/hs rows (80B, 16B-aligned)

__global__ __launch_bounds__(256, 2) void attn_v6(
    const short* __restrict__ fK,    // keys    [B*N,64]
    const short* __restrict__ gQ,    // queries [B*N,64] (pre-scaled by log2e)
    const short* __restrict__ hT,    // values  [B,256,4096]
    short* __restrict__ oPart,       // [nsplit][B*N,256] bf16
    float* __restrict__ lPart,       // [nsplit][B*N]
    int sbits)                       // log2(nsplit)
{
    const int bx = blockIdx.x;
    const int s  = bx & ((1 << sbits) - 1);
    const int vh = (bx >> sbits) & 1;            // vch half
    const int qt = (bx >> (sbits + 1)) & 31;     // q tile (128 q)
    const int b  = bx >> (sbits + 6);
    const int kb = s << (12 - sbits);            // key base
    const int niter = 64 >> sbits;               // tiles of 64 keys
    const int t  = threadIdx.x;
    const int w  = t >> 6, lane = t & 63;
    const int l31 = lane & 31, h = lane >> 5;
    const int q_wave = qt * 128 + w * 32;        // each wave: 32 q

    __shared__ short fs[2][64 * HST];
    __shared__ short hs[2][128 * HST];

    // Q B-frags (B[k=d][n=q]: n=l31, k=8h+j), held all kernel
    bf16x8 qf[4];
    #pragma unroll
    for (int k = 0; k < 4; k++)
        qf[k] = *(const bf16x8*)&gQ[(size_t)(b * N_ + q_wave + l31) * 64 + k * 16 + h * 8];

    floatx16 oacc[4];
    #pragma unroll
    for (int vt = 0; vt < 4; vt++)
        #pragma unroll
        for (int j = 0; j < 16; j++) oacc[vt][j] = 0.f;
    float lsum = 0.f;

    // staging geometry
    const int f_row = t >> 2, f_c = (t & 3) * 16;   // fs: 2 b128 at f_c, f_c+8
    const int h_row = t >> 3, h_c = (t & 7) * 8;    // hs: rows h_row + 32*i, i<4

    // prologue: stage tile 0
    {
        *(bf16x8*)&fs[0][f_row * HST + f_c] =
            *(const bf16x8*)&fK[(size_t)(b * N_ + kb + f_row) * 64 + f_c];
        *(bf16x8*)&fs[0][f_row * HST + f_c + 8] =
            *(const bf16x8*)&fK[(size_t)(b * N_ + kb + f_row) * 64 + f_c + 8];
        #pragma unroll
        for (int i = 0; i < 4; i++)
            *(bf16x8*)&hs[0][(h_row + i * 32) * HST + h_c] =
                *(const bf16x8*)&hT[((size_t)(b * 256 + vh * 128 + h_row + i * 32)) * 4096 + kb + h_c];
    }
    __syncthreads();

    for (int it = 0; it < niter; ++it) {
        const int cur = it & 1;
        const bool more = (it < niter - 1);
        const int kn = kb + (it + 1) * 64;

        // prefetch next tile to registers (async-STAGE: issue early, commit late)
        bf16x8 rf0, rf1, rh[4];
        if (more) {
            rf0 = *(const bf16x8*)&fK[(size_t)(b * N_ + kn + f_row) * 64 + f_c];
            rf1 = *(const bf16x8*)&fK[(size_t)(b * N_ + kn + f_row) * 64 + f_c + 8];
            #pragma unroll
            for (int i = 0; i < 4; i++)
                rh[i] = *(const bf16x8*)&hT[((size_t)(b * 256 + vh * 128 + h_row + i * 32)) * 4096 + kn + h_c];
        }

        // ---- S^T = F @ Q^T : tiles [m=key32] x this wave's 32 q ----
        bf16x8 ffr[2][4];
        #pragma unroll
        for (int m = 0; m < 2; m++)
            #pragma unroll
            for (int k = 0; k < 4; k++)
                ffr[m][k] = *(const bf16x8*)&fs[cur][(m * 32 + l31) * HST + k * 16 + h * 8];

        floatx16 sacc[2];
        __builtin_amdgcn_s_setprio(1);
        #pragma unroll
        for (int m = 0; m < 2; m++) {
            #pragma unroll
            for (int j = 0; j < 16; j++) sacc[m][j] = 0.f;
            #pragma unroll
            for (int k = 0; k < 4; k++)
                sacc[m] = __builtin_amdgcn_mfma_f32_32x32x16_bf16(
                    ffr[m][k], qf[k], sacc[m], 0, 0, 0);
        }
        __builtin_amdgcn_s_setprio(0);

        // ---- exp2 + in-register transpose to PV A-frags ----
        bf16x8 pfrag[4];   // [kstep 0..3]
        #pragma unroll
        for (int m = 0; m < 2; m++) {
            float p[16]; float ps_ = 0.f;
            #pragma unroll
            for (int j = 0; j < 16; j++) {
                p[j] = __builtin_amdgcn_exp2f(sacc[m][j]);
                ps_ += p[j];
            }
            ps_ += __shfl_xor(ps_, 32);
            lsum += ps_;
            unsigned pk[8];
            #pragma unroll
            for (int i = 0; i < 8; i++) pk[i] = cvtpk(p[2 * i], p[2 * i + 1]);
            #pragma unroll
            for (int kp = 0; kp < 2; kp++) {
                uint32x2 r0 = __builtin_amdgcn_permlane32_swap(pk[4 * kp],     pk[4 * kp + 2], false, false);
                uint32x2 r1 = __builtin_amdgcn_permlane32_swap(pk[4 * kp + 1], pk[4 * kp + 3], false, false);
                U8 u; u.u[0] = r0[0]; u.u[1] = r1[0]; u.u[2] = r0[1]; u.u[3] = r1[1];
                pfrag[m * 2 + kp] = u.v;
            }
        }

        // ---- O += P @ V : wave covers its 32 q x the block's 128 vch ----
        __builtin_amdgcn_s_setprio(1);
        #pragma unroll
        for (int kk2 = 0; kk2 < 4; kk2++)
            #pragma unroll
            for (int vt = 0; vt < 4; vt++) {
                bf16x8 vfr = *(const bf16x8*)&hs[cur][(vt * 32 + l31) * HST + kk2 * 16 + h * 8];
                oacc[vt] = __builtin_amdgcn_mfma_f32_32x32x16_bf16(
                    pfrag[kk2], vfr, oacc[vt], 0, 0, 0);
            }
        __builtin_amdgcn_s_setprio(0);

        // ---- commit prefetch to other buffer ----
        if (more) {
            const int nxt = cur ^ 1;
            *(bf16x8*)&fs[nxt][f_row * HST + f_c] = rf0;
            *(bf16x8*)&fs[nxt][f_row * HST + f_c + 8] = rf1;
            #pragma unroll
            for (int i = 0; i < 4; i++)
                *(bf16x8*)&hs[nxt][(h_row + i * 32) * HST + h_c] = rh[i];
        }
        __syncthreads();
    }

    // ---- epilogue: store partial O (bf16) and partial l ----
    #pragma unroll
    for (int vt = 0; vt < 4; vt++) {
        int vch = vh * 128 + vt * 32 + l31;
        #pragma unroll
        for (int r = 0; r < 16; r++) {
            int q = q_wave + (r & 3) + 8 * (r >> 2) + 4 * h;
            oPart[(size_t)s * 4194304 + (size_t)(b * N_ + q) * 256 + vch] = f2bf(oacc[vt][r]);
        }
    }
    // lsum identical across vh-blocks; write from vh==0 only
    if (vh == 0 && lane < 32)
        lPart[(size_t)s * 16384 + b * N_ + q_wave + lane] = lsum;
}

// ---------------------------------------------------------------------------
// Kernel 3: fused combine + output GEMM + residual, raw-Wo input.
// out = gamma*(((O0+O1)/(l0+l1)) @ Wo + bo) + x.   64x256 tiles,
// grid (2,256)=512 blocks = 2/CU.  Wo fp32 transpose-staged into Bs
// (coalesced float4 n-reads + b16 scatter-writes), no WoT prep.
// ---------------------------------------------------------------------------
__global__ __launch_bounds__(256, 2) void out_mfma(
    const short* __restrict__ oPart, const float* __restrict__ lPart,
    const float* __restrict__ Wo,
    const float* __restrict__ bo, const float* __restrict__ x,
    const float* __restrict__ gamma, float* __restrict__ out)
{
    const int n0 = blockIdx.x * 256;
    const int m0 = blockIdx.y * 64;
    const int t  = threadIdx.x;
    const int w  = t >> 6, lane = t & 63;
    const int l15 = lane & 15, quad = lane >> 4;
    const int wm = w & 1, wn = w >> 1;   // wave: 32 rows x 128 cols

    __shared__ short As[64 * 40];
    __shared__ short Bs[256 * 40];
    __shared__ float linv[64];

    if (t < 64)
        linv[t] = 1.0f / (lPart[m0 + t] + lPart[16384 + m0 + t]);

    const int kk = t >> 3;               // 0..31
    const int nl = (t & 7) * 32;         // 0..224 (n within 256-col block)
    const int arow = t >> 2, ako = (t & 3) * 8;

    floatx4 acc[2][8];
    #pragma unroll
    for (int i = 0; i < 2; i++)
        #pragma unroll
        for (int j = 0; j < 8; j++) acc[i][j] = (floatx4){0.f,0.f,0.f,0.f};

    __syncthreads();

    for (int k0 = 0; k0 < C2_; k0 += 32) {
        {   // As fused combine: 64 rows x 32 k, 8 elems/thread
            size_t gb = (size_t)(m0 + arow) * 256 + k0 + ako;
            bf16x8 o0 = *(const bf16x8*)&oPart[gb];
            bf16x8 o1 = *(const bf16x8*)&oPart[4194304 + gb];
            float li = linv[arow];
            U8 u;
            #pragma unroll
            for (int j = 0; j < 4; j++) {
                float a0 = (bf2f(o0[2 * j])     + bf2f(o1[2 * j]))     * li;
                float a1 = (bf2f(o0[2 * j + 1]) + bf2f(o1[2 * j + 1])) * li;
                u.u[j] = cvtpk(a0, a1);
            }
            *(bf16x8*)&As[arow * 40 + ako] = u.v;
        }
        {   // Bs: transpose-stage 32 n at one k from raw Wo
            const float* rp = &Wo[(size_t)(k0 + kk) * 512 + n0 + nl];
            #pragma unroll
            for (int i = 0; i < 8; i++) {
                float4 wv = *(const float4*)&rp[i * 4];
                Bs[(nl + i * 4 + 0) * 40 + kk] = f2bf(wv.x);
                Bs[(nl + i * 4 + 1) * 40 + kk] = f2bf(wv.y);
                Bs[(nl + i * 4 + 2) * 40 + kk] = f2bf(wv.z);
                Bs[(nl + i * 4 + 3) * 40 + kk] = f2bf(wv.w);
            }
        }
        __syncthreads();

        bf16x8 af[2], bfr[8];
        #pragma unroll
        for (int mt = 0; mt < 2; mt++)
            af[mt] = *(const bf16x8*)&As[(wm * 32 + mt * 16 + l15) * 40 + quad * 8];
        #pragma unroll
        for (int nt = 0; nt < 8; nt++)
            bfr[nt] = *(const bf16x8*)&Bs[(wn * 128 + nt * 16 + l15) * 40 + quad * 8];
        #pragma unroll
        for (int mt = 0; mt < 2; mt++)
            #pragma unroll
            for (int nt = 0; nt < 8; nt++)
                acc[mt][nt] = __builtin_amdgcn_mfma_f32_16x16x32_bf16(af[mt], bfr[nt], acc[mt][nt], 0, 0, 0);
        __syncthreads();
    }

    const float gm = gamma[0];
    #pragma unroll
    for (int mt = 0; mt < 2; mt++) {
        #pragma unroll
        for (int nt = 0; nt < 8; nt++) {
            int col = n0 + wn * 128 + nt * 16 + l15;
            float bias = bo[col];
            #pragma unroll
            for (int rg = 0; rg < 4; rg++) {
                int row = m0 + wm * 32 + mt * 16 + quad * 4 + rg;
                out[(size_t)row * C_ + col] =
                    gm * (acc[mt][nt][rg] + bias) + x[(size_t)row * C_ + col];
            }
        }
    }
}

// ---------------------------------------------------------------------------
extern "C" void kernel_launch(void* const* d_in, const int* in_sizes, int n_in,
                              void* d_out, int out_size, void* d_ws, size_t ws_size,
                              hipStream_t stream) {
    (void)in_sizes; (void)n_in; (void)out_size; (void)ws_size;

    const float* x     = (const float*)d_in[0];
    const float* Wf    = (const float*)d_in[1];
    const float* bfv   = (const float*)d_in[2];
    const float* Wg    = (const float*)d_in[3];
    const float* bgv   = (const float*)d_in[4];
    const float* Wh    = (const float*)d_in[5];
    const float* bhv   = (const float*)d_in[6];
    const float* Wo    = (const float*)d_in[7];
    const float* bo    = (const float*)d_in[8];
    const float* gamma = (const float*)d_in[9];
    float* out = (float*)d_out;

    // ws layout (shorts): fbf 1M | gbf 1M | hT 4.2M | oPart 2x4.2M (bf16)
    // then fp32 lPart 2x16K.  Total ~29.5 MB.
    short* fbf   = (short*)d_ws;
    short* gbf   = fbf   + (size_t)B_ * N_ * C8_;
    short* hT    = gbf   + (size_t)B_ * N_ * C8_;
    short* oPart = hT    + (size_t)B_ * C2_ * N_;
    float* lPart = (float*)(oPart + (size_t)2 * 16384 * 256);

    const int sbits = 1;                 // nsplit=2: one grid round of 512 blocks

    qkv_mfma<<<dim3(3, 256), 256, 0, stream>>>(x, Wf, Wg, Wh, bfv, bgv, bhv, fbf, gbf, hT);
    attn_v6<<<256 << sbits, 256, 0, stream>>>(fbf, gbf, hT, oPart, lPart, sbits);
    out_mfma<<<dim3(2, 256), 256, 0, stream>>>(oPart, lPart, Wo, bo, x, gamma, out);
}

// Round 8
// 194.407 us; speedup vs baseline: 1.1264x; 1.1264x over previous
//
#include <hip/hip_runtime.h>
#include <math.h>

#define B_   4
#define N_   4096
#define C_   512
#define C8_  64
#define C2_  256
#define LOG2E 1.4426950408889634f

typedef __attribute__((ext_vector_type(8))) short bf16x8;
typedef __attribute__((ext_vector_type(4))) short bf16x4;
typedef __attribute__((ext_vector_type(4))) float floatx4;
typedef __attribute__((ext_vector_type(16))) float floatx16;
typedef __attribute__((ext_vector_type(2))) unsigned uint32x2;

__device__ __forceinline__ short f2bf(float x) {
    unsigned u = __float_as_uint(x);
    u += 0x7fff + ((u >> 16) & 1);          // round-to-nearest-even
    return (short)(u >> 16);
}
__device__ __forceinline__ unsigned cvtpk(float a, float b) {
    unsigned r;
    asm("v_cvt_pk_bf16_f32 %0, %1, %2" : "=v"(r) : "v"(a), "v"(b));
    return r;   // lo = bf16(a), hi = bf16(b)
}
__device__ __forceinline__ float bf2f(short s) {
    return __uint_as_float(((unsigned)(unsigned short)s) << 16);
}

union U8 { bf16x8 v; unsigned u[4]; };
union U4 { bf16x4 v; unsigned u[2]; };

// ---------------------------------------------------------------------------
// Kernel 0: weight prep (W only — xbf removed; qkv converts x inline).
// WcatT[384][512] = [Wf|Wg|Wh]^T,  WoT[512][256] = Wo^T.
// ---------------------------------------------------------------------------
__global__ __launch_bounds__(256) void convert_w(
    const float* __restrict__ Wf, const float* __restrict__ Wg,
    const float* __restrict__ Wh, const float* __restrict__ Wo,
    short* __restrict__ WcatT, short* __restrict__ WoT)
{
    int tid = blockIdx.x * 256 + threadIdx.x;
    if (tid < 384 * 512) {
        int n = tid >> 9, k = tid & 511;
        float v = (n < 64)  ? Wf[k * 64 + n]
                : (n < 128) ? Wg[k * 64 + (n - 64)]
                            : Wh[k * 256 + (n - 128)];
        WcatT[tid] = f2bf(v);
    } else {
        int t2 = tid - 384 * 512;      // < 512*256
        int n = t2 >> 8, k = t2 & 255;
        WoT[t2] = f2bf(Wo[k * 512 + n]);
    }
}

// ---------------------------------------------------------------------------
// Kernel 1: qkv MFMA GEMM.  As: x fp32 -> cvtpk -> bf16 inline (proven
// rounds 0-5; removes the xbf materialization round-trip).  Bs: WcatT bf16,
// vectorized b128 staging (R7's in-kernel W transpose had 8-way LDS write
// conflicts — reverted).  64x128 tiles, grid (3,256)=768 blocks = 3/CU,
// LB(256,3).  g pre-scaled by log2(e) for exp2-direct softmax.
// ---------------------------------------------------------------------------
__global__ __launch_bounds__(256, 3) void qkv_mfma(
    const float* __restrict__ x, const short* __restrict__ WcatT,
    const float* __restrict__ bfv, const float* __restrict__ bgv,
    const float* __restrict__ bhv,
    short* __restrict__ fbf, short* __restrict__ gbf, short* __restrict__ hT)
{
    const int ny = blockIdx.x;           // 0..2
    const int m0 = blockIdx.y * 64;
    const int n0 = ny * 128;
    const int t  = threadIdx.x;
    const int w  = t >> 6, lane = t & 63;
    const int l15 = lane & 15, quad = lane >> 4;
    const int wm = w & 1, wn = w >> 1;   // wave: 32 rows x 64 cols

    __shared__ short As[64 * 40];
    __shared__ short Bs[128 * 40];

    const int arow = t >> 2, ako = (t & 3) * 8;   // As: 8 k-elems per thread

    floatx4 acc[2][4];
    #pragma unroll
    for (int i = 0; i < 2; i++)
        #pragma unroll
        for (int j = 0; j < 4; j++) acc[i][j] = (floatx4){0.f,0.f,0.f,0.f};

    for (int k0 = 0; k0 < C_; k0 += 32) {
        {   // As: 64 rows x 32 k from x fp32, convert inline
            const float* xp = &x[(size_t)(m0 + arow) * C_ + k0 + ako];
            float4 v0 = *(const float4*)xp;
            float4 v1 = *(const float4*)(xp + 4);
            U8 ua;
            ua.u[0] = cvtpk(v0.x, v0.y); ua.u[1] = cvtpk(v0.z, v0.w);
            ua.u[2] = cvtpk(v1.x, v1.y); ua.u[3] = cvtpk(v1.z, v1.w);
            *(bf16x8*)&As[arow * 40 + ako] = ua.v;
        }
        #pragma unroll
        for (int i = 0; i < 2; i++) {    // Bs: 128 rows x 32 k (bf16, b128)
            int c = t + i * 256;
            int nr = c >> 2, ko = (c & 3) * 8;
            *(bf16x8*)&Bs[nr * 40 + ko] =
                *(const bf16x8*)&WcatT[(size_t)(n0 + nr) * 512 + k0 + ko];
        }
        __syncthreads();

        bf16x8 af[2], bfr[4];
        #pragma unroll
        for (int mt = 0; mt < 2; mt++)
            af[mt] = *(const bf16x8*)&As[(wm * 32 + mt * 16 + l15) * 40 + quad * 8];
        #pragma unroll
        for (int nt = 0; nt < 4; nt++)
            bfr[nt] = *(const bf16x8*)&Bs[(wn * 64 + nt * 16 + l15) * 40 + quad * 8];
        #pragma unroll
        for (int mt = 0; mt < 2; mt++)
            #pragma unroll
            for (int nt = 0; nt < 4; nt++)
                acc[mt][nt] = __builtin_amdgcn_mfma_f32_16x16x32_bf16(af[mt], bfr[nt], acc[mt][nt], 0, 0, 0);
        __syncthreads();
    }

    if (ny == 0) {
        #pragma unroll
        for (int mt = 0; mt < 2; mt++) {
            #pragma unroll
            for (int nt = 0; nt < 4; nt++) {
                int cn = wn * 64 + nt * 16 + l15;
                #pragma unroll
                for (int rg = 0; rg < 4; rg++) {
                    int row = m0 + wm * 32 + mt * 16 + quad * 4 + rg;
                    float v = acc[mt][nt][rg];
                    if (cn < 64) fbf[(size_t)row * 64 + cn]        = f2bf(v + bfv[cn]);
                    else         gbf[(size_t)row * 64 + (cn - 64)] = f2bf((v + bgv[cn - 64]) * LOG2E);
                }
            }
        }
    } else {
        #pragma unroll
        for (int mt = 0; mt < 2; mt++) {
            #pragma unroll
            for (int nt = 0; nt < 4; nt++) {
                int hch = (ny - 1) * 128 + wn * 64 + nt * 16 + l15;
                int row = m0 + wm * 32 + mt * 16 + quad * 4;
                int bb = row >> 12, n = row & 4095;
                float bias = bhv[hch];
                U4 pk;
                pk.u[0] = cvtpk(acc[mt][nt][0] + bias, acc[mt][nt][1] + bias);
                pk.u[1] = cvtpk(acc[mt][nt][2] + bias, acc[mt][nt][3] + bias);
                *(bf16x4*)&hT[((size_t)(bb * 256 + hch)) * 4096 + n] = pk.v;
            }
        }
    }
}

// ---------------------------------------------------------------------------
// Kernel 2: attention v6 (UNCHANGED — proven 66.7 µs, Occ ~20%, 0 bank
// conflicts, WRITE 16.5 MB).  Per-wave 32 q x 128 vch; ~184 unified regs ->
// 2 blocks/CU.  nsplit=2, 512 blocks, partial O in bf16.
// ---------------------------------------------------------------------------
#define HST 40   // short stride for fs/hs rows (80B, 16B-aligned)

__global__ __launch_bounds__(256, 2) void attn_v6(
    const short* __restrict__ fK,    // keys    [B*N,64]
    const short* __restrict__ gQ,    // queries [B*N,64] (pre-scaled by log2e)
    const short* __restrict__ hT,    // values  [B,256,4096]
    short* __restrict__ oPart,       // [nsplit][B*N,256] bf16
    float* __restrict__ lPart,       // [nsplit][B*N]
    int sbits)                       // log2(nsplit)
{
    const int bx = blockIdx.x;
    const int s  = bx & ((1 << sbits) - 1);
    const int vh = (bx >> sbits) & 1;            // vch half
    const int qt = (bx >> (sbits + 1)) & 31;     // q tile (128 q)
    const int b  = bx >> (sbits + 6);
    const int kb = s << (12 - sbits);            // key base
    const int niter = 64 >> sbits;               // tiles of 64 keys
    const int t  = threadIdx.x;
    const int w  = t >> 6, lane = t & 63;
    const int l31 = lane & 31, h = lane >> 5;
    const int q_wave = qt * 128 + w * 32;        // each wave: 32 q

    __shared__ short fs[2][64 * HST];
    __shared__ short hs[2][128 * HST];

    // Q B-frags (B[k=d][n=q]: n=l31, k=8h+j), held all kernel
    bf16x8 qf[4];
    #pragma unroll
    for (int k = 0; k < 4; k++)
        qf[k] = *(const bf16x8*)&gQ[(size_t)(b * N_ + q_wave + l31) * 64 + k * 16 + h * 8];

    floatx16 oacc[4];
    #pragma unroll
    for (int vt = 0; vt < 4; vt++)
        #pragma unroll
        for (int j = 0; j < 16; j++) oacc[vt][j] = 0.f;
    float lsum = 0.f;

    // staging geometry
    const int f_row = t >> 2, f_c = (t & 3) * 16;   // fs: 2 b128 at f_c, f_c+8
    const int h_row = t >> 3, h_c = (t & 7) * 8;    // hs: rows h_row + 32*i, i<4

    // prologue: stage tile 0
    {
        *(bf16x8*)&fs[0][f_row * HST + f_c] =
            *(const bf16x8*)&fK[(size_t)(b * N_ + kb + f_row) * 64 + f_c];
        *(bf16x8*)&fs[0][f_row * HST + f_c + 8] =
            *(const bf16x8*)&fK[(size_t)(b * N_ + kb + f_row) * 64 + f_c + 8];
        #pragma unroll
        for (int i = 0; i < 4; i++)
            *(bf16x8*)&hs[0][(h_row + i * 32) * HST + h_c] =
                *(const bf16x8*)&hT[((size_t)(b * 256 + vh * 128 + h_row + i * 32)) * 4096 + kb + h_c];
    }
    __syncthreads();

    for (int it = 0; it < niter; ++it) {
        const int cur = it & 1;
        const bool more = (it < niter - 1);
        const int kn = kb + (it + 1) * 64;

        // prefetch next tile to registers (async-STAGE: issue early, commit late)
        bf16x8 rf0, rf1, rh[4];
        if (more) {
            rf0 = *(const bf16x8*)&fK[(size_t)(b * N_ + kn + f_row) * 64 + f_c];
            rf1 = *(const bf16x8*)&fK[(size_t)(b * N_ + kn + f_row) * 64 + f_c + 8];
            #pragma unroll
            for (int i = 0; i < 4; i++)
                rh[i] = *(const bf16x8*)&hT[((size_t)(b * 256 + vh * 128 + h_row + i * 32)) * 4096 + kn + h_c];
        }

        // ---- S^T = F @ Q^T : tiles [m=key32] x this wave's 32 q ----
        bf16x8 ffr[2][4];
        #pragma unroll
        for (int m = 0; m < 2; m++)
            #pragma unroll
            for (int k = 0; k < 4; k++)
                ffr[m][k] = *(const bf16x8*)&fs[cur][(m * 32 + l31) * HST + k * 16 + h * 8];

        floatx16 sacc[2];
        __builtin_amdgcn_s_setprio(1);
        #pragma unroll
        for (int m = 0; m < 2; m++) {
            #pragma unroll
            for (int j = 0; j < 16; j++) sacc[m][j] = 0.f;
            #pragma unroll
            for (int k = 0; k < 4; k++)
                sacc[m] = __builtin_amdgcn_mfma_f32_32x32x16_bf16(
                    ffr[m][k], qf[k], sacc[m], 0, 0, 0);
        }
        __builtin_amdgcn_s_setprio(0);

        // ---- exp2 + in-register transpose to PV A-frags ----
        bf16x8 pfrag[4];   // [kstep 0..3]
        #pragma unroll
        for (int m = 0; m < 2; m++) {
            float p[16]; float ps_ = 0.f;
            #pragma unroll
            for (int j = 0; j < 16; j++) {
                p[j] = __builtin_amdgcn_exp2f(sacc[m][j]);
                ps_ += p[j];
            }
            ps_ += __shfl_xor(ps_, 32);
            lsum += ps_;
            unsigned pk[8];
            #pragma unroll
            for (int i = 0; i < 8; i++) pk[i] = cvtpk(p[2 * i], p[2 * i + 1]);
            #pragma unroll
            for (int kp = 0; kp < 2; kp++) {
                uint32x2 r0 = __builtin_amdgcn_permlane32_swap(pk[4 * kp],     pk[4 * kp + 2], false, false);
                uint32x2 r1 = __builtin_amdgcn_permlane32_swap(pk[4 * kp + 1], pk[4 * kp + 3], false, false);
                U8 u; u.u[0] = r0[0]; u.u[1] = r1[0]; u.u[2] = r0[1]; u.u[3] = r1[1];
                pfrag[m * 2 + kp] = u.v;
            }
        }

        // ---- O += P @ V : wave covers its 32 q x the block's 128 vch ----
        __builtin_amdgcn_s_setprio(1);
        #pragma unroll
        for (int kk2 = 0; kk2 < 4; kk2++)
            #pragma unroll
            for (int vt = 0; vt < 4; vt++) {
                bf16x8 vfr = *(const bf16x8*)&hs[cur][(vt * 32 + l31) * HST + kk2 * 16 + h * 8];
                oacc[vt] = __builtin_amdgcn_mfma_f32_32x32x16_bf16(
                    pfrag[kk2], vfr, oacc[vt], 0, 0, 0);
            }
        __builtin_amdgcn_s_setprio(0);

        // ---- commit prefetch to other buffer ----
        if (more) {
            const int nxt = cur ^ 1;
            *(bf16x8*)&fs[nxt][f_row * HST + f_c] = rf0;
            *(bf16x8*)&fs[nxt][f_row * HST + f_c + 8] = rf1;
            #pragma unroll
            for (int i = 0; i < 4; i++)
                *(bf16x8*)&hs[nxt][(h_row + i * 32) * HST + h_c] = rh[i];
        }
        __syncthreads();
    }

    // ---- epilogue: store partial O (bf16) and partial l ----
    #pragma unroll
    for (int vt = 0; vt < 4; vt++) {
        int vch = vh * 128 + vt * 32 + l31;
        #pragma unroll
        for (int r = 0; r < 16; r++) {
            int q = q_wave + (r & 3) + 8 * (r >> 2) + 4 * h;
            oPart[(size_t)s * 4194304 + (size_t)(b * N_ + q) * 256 + vch] = f2bf(oacc[vt][r]);
        }
    }
    // lsum identical across vh-blocks; write from vh==0 only
    if (vh == 0 && lane < 32)
        lPart[(size_t)s * 16384 + b * N_ + q_wave + lane] = lsum;
}

// ---------------------------------------------------------------------------
// Kernel 3: fused combine + output GEMM + residual (UNCHANGED from R6).
// out = gamma*(((O0+O1)/(l0+l1)) @ Wo + bo) + x.   64x256 tiles,
// grid (2,256)=512 blocks = 2/CU.
// ---------------------------------------------------------------------------
__global__ __launch_bounds__(256, 2) void out_mfma(
    const short* __restrict__ oPart, const float* __restrict__ lPart,
    const short* __restrict__ WoT,
    const float* __restrict__ bo, const float* __restrict__ x,
    const float* __restrict__ gamma, float* __restrict__ out)
{
    const int n0 = blockIdx.x * 256;
    const int m0 = blockIdx.y * 64;
    const int t  = threadIdx.x;
    const int w  = t >> 6, lane = t & 63;
    const int l15 = lane & 15, quad = lane >> 4;
    const int wm = w & 1, wn = w >> 1;   // wave: 32 rows x 128 cols

    __shared__ short As[64 * 40];
    __shared__ short Bs[256 * 40];
    __shared__ float linv[64];

    if (t < 64)
        linv[t] = 1.0f / (lPart[m0 + t] + lPart[16384 + m0 + t]);

    const int arow = t >> 2, ako = (t & 3) * 8;

    floatx4 acc[2][8];
    #pragma unroll
    for (int i = 0; i < 2; i++)
        #pragma unroll
        for (int j = 0; j < 8; j++) acc[i][j] = (floatx4){0.f,0.f,0.f,0.f};

    __syncthreads();

    for (int k0 = 0; k0 < C2_; k0 += 32) {
        {   // As fused combine: 64 rows x 32 k, 8 elems/thread
            size_t gb = (size_t)(m0 + arow) * 256 + k0 + ako;
            bf16x8 o0 = *(const bf16x8*)&oPart[gb];
            bf16x8 o1 = *(const bf16x8*)&oPart[4194304 + gb];
            float li = linv[arow];
            U8 u;
            #pragma unroll
            for (int j = 0; j < 4; j++) {
                float a0 = (bf2f(o0[2 * j])     + bf2f(o1[2 * j]))     * li;
                float a1 = (bf2f(o0[2 * j + 1]) + bf2f(o1[2 * j + 1])) * li;
                u.u[j] = cvtpk(a0, a1);
            }
            *(bf16x8*)&As[arow * 40 + ako] = u.v;
        }
        #pragma unroll
        for (int i = 0; i < 4; i++) {    // Bs: 256 n-rows x 32 k
            int c = t + i * 256;
            int nr = c >> 2, ko = (c & 3) * 8;
            *(bf16x8*)&Bs[nr * 40 + ko] =
                *(const bf16x8*)&WoT[(size_t)(n0 + nr) * 256 + k0 + ko];
        }
        __syncthreads();

        bf16x8 af[2], bfr[8];
        #pragma unroll
        for (int mt = 0; mt < 2; mt++)
            af[mt] = *(const bf16x8*)&As[(wm * 32 + mt * 16 + l15) * 40 + quad * 8];
        #pragma unroll
        for (int nt = 0; nt < 8; nt++)
            bfr[nt] = *(const bf16x8*)&Bs[(wn * 128 + nt * 16 + l15) * 40 + quad * 8];
        #pragma unroll
        for (int mt = 0; mt < 2; mt++)
            #pragma unroll
            for (int nt = 0; nt < 8; nt++)
                acc[mt][nt] = __builtin_amdgcn_mfma_f32_16x16x32_bf16(af[mt], bfr[nt], acc[mt][nt], 0, 0, 0);
        __syncthreads();
    }

    const float gm = gamma[0];
    #pragma unroll
    for (int mt = 0; mt < 2; mt++) {
        #pragma unroll
        for (int nt = 0; nt < 8; nt++) {
            int col = n0 + wn * 128 + nt * 16 + l15;
            float bias = bo[col];
            #pragma unroll
            for (int rg = 0; rg < 4; rg++) {
                int row = m0 + wm * 32 + mt * 16 + quad * 4 + rg;
                out[(size_t)row * C_ + col] =
                    gm * (acc[mt][nt][rg] + bias) + x[(size_t)row * C_ + col];
            }
        }
    }
}

// ---------------------------------------------------------------------------
extern "C" void kernel_launch(void* const* d_in, const int* in_sizes, int n_in,
                              void* d_out, int out_size, void* d_ws, size_t ws_size,
                              hipStream_t stream) {
    (void)in_sizes; (void)n_in; (void)out_size; (void)ws_size;

    const float* x     = (const float*)d_in[0];
    const float* Wf    = (const float*)d_in[1];
    const float* bfv   = (const float*)d_in[2];
    const float* Wg    = (const float*)d_in[3];
    const float* bgv   = (const float*)d_in[4];
    const float* Wh    = (const float*)d_in[5];
    const float* bhv   = (const float*)d_in[6];
    const float* Wo    = (const float*)d_in[7];
    const float* bo    = (const float*)d_in[8];
    const float* gamma = (const float*)d_in[9];
    float* out = (float*)d_out;

    // ws layout (shorts): fbf 1M | gbf 1M | hT 4.2M | WcatT 192K | WoT 128K |
    // oPart 2x4.2M (bf16) ; then fp32 lPart 2x16K.  Total ~30 MB.
    short* fbf   = (short*)d_ws;
    short* gbf   = fbf   + (size_t)B_ * N_ * C8_;
    short* hT    = gbf   + (size_t)B_ * N_ * C8_;
    short* WcatT = hT    + (size_t)B_ * C2_ * N_;
    short* WoT   = WcatT + (size_t)384 * 512;
    short* oPart = WoT   + (size_t)512 * 256;
    float* lPart = (float*)(oPart + (size_t)2 * 16384 * 256);

    const int sbits = 1;                 // nsplit=2: one grid round of 512 blocks

    convert_w<<<1280, 256, 0, stream>>>(Wf, Wg, Wh, Wo, WcatT, WoT);
    qkv_mfma<<<dim3(3, 256), 256, 0, stream>>>(x, WcatT, bfv, bgv, bhv, fbf, gbf, hT);
    attn_v6<<<256 << sbits, 256, 0, stream>>>(fbf, gbf, hT, oPart, lPart, sbits);
    out_mfma<<<dim3(2, 256), 256, 0, stream>>>(oPart, lPart, WoT, bo, x, gamma, out);
}